// Round 5
// baseline (3328.777 us; speedup 1.0000x reference)
//
#include <hip/hip_runtime.h>

// SineLSTM R5: 128-thread blocks (2 waves), 2 gate rows per thread.
// Rationale: per-wave h-broadcast cost from LDS is independent of rows/lane,
// so halving the wave count halves the dominant LDS-broadcast traffic
// (R2: 4 waves x 150 elems; R5: 2 waves x 104 elems w/ h1-reuse fusion).
// __launch_bounds__(128,1) -> 1 wave/SIMD -> 512 unified regs/thread:
// 312 padded weights + accums + temps ~ 370 fits (R4 spilled at 256 budget;
// FETCH_SIZE 68MB was the smoking gun). c2 is VGPR-resident in wave1, which
// owns U2 + output reduce exclusively (no stale-c2 redundant compute).
// Teacher region: 2 barriers/step; predict region (33 iters): 4 barriers.

#define Hh   50
#define G4   200
#define TLEN 1024
#define KP   52      // weights zero-padded to 52 = 13 float4
#define NT   128     // threads per block = 2 waves

extern "C" __global__ __launch_bounds__(NT, 1)
void sine_lstm_kernel(const float* __restrict__ x,
                      const float* __restrict__ W_ih1,
                      const float* __restrict__ W_hh1,
                      const float* __restrict__ b_ih1,
                      const float* __restrict__ b_hh1,
                      const float* __restrict__ W_ih2,
                      const float* __restrict__ W_hh2,
                      const float* __restrict__ b_ih2,
                      const float* __restrict__ b_hh2,
                      const float* __restrict__ W_lin,
                      const float* __restrict__ b_lin,
                      const int*   __restrict__ predict_p,
                      float* __restrict__ out,
                      int T)
{
    __shared__ __align__(16) float x_lds[TLEN];
    __shared__ __align__(16) float h1buf[64], h2buf[64];   // 50..63 stay 0
    __shared__ __align__(16) float g1[G4], g2[G4];          // PRE-ACTIVATED
    __shared__ float o_lds;

    const int tid = threadIdx.x;
    const int b   = blockIdx.x;
    const int predict = *predict_p;
    const int S = T + predict;

    for (int i = tid; i < TLEN; i += NT)
        x_lds[i] = x[(size_t)b * T + i];
    if (tid < 64) { h1buf[tid] = 0.0f; h2buf[tid] = 0.0f; }

    // ---- two gate rows per thread: r0 = tid, r1 = tid + 128 (clamped) ----
    const int r0 = tid;
    const int r1 = tid + NT;
    const int r1c = (r1 < G4) ? r1 : (G4 - 1);
    const bool wr1 = (r1 < G4);
    const int rows[2] = { r0, r1c };

    float w1[2][KP], wi2[2][KP], wh2[2][KP];
    float wih[2], bb1[2], bb2[2], mg[2];
    #pragma unroll
    for (int rr = 0; rr < 2; ++rr) {
        const int r = rows[rr];
        wih[rr] = W_ih1[r];
        bb1[rr] = b_ih1[r] + b_hh1[r];
        bb2[rr] = b_ih2[r] + b_hh2[r];
        mg[rr]  = (r >= 2 * Hh && r < 3 * Hh) ? 2.0f : 1.0f;  // tanh for g-gate
        for (int k = 0; k < Hh; ++k) {
            w1[rr][k]  = W_hh1[r * Hh + k];
            wi2[rr][k] = W_ih2[r * Hh + k];
            wh2[rr][k] = W_hh2[r * Hh + k];
        }
        for (int k = Hh; k < KP; ++k) { w1[rr][k] = 0.0f; wi2[rr][k] = 0.0f; wh2[rr][k] = 0.0f; }
    }

    const int wv = tid >> 6;     // 0 or 1
    const int ln = tid & 63;
    const float wlin_l = (ln < Hh) ? W_lin[ln] : 0.0f;
    const float blin   = b_lin[0];

    float c1r = 0.0f;            // layer-1 cell: wave0 lanes<50
    float c2r = 0.0f;            // layer-2 cell: wave1 lanes<50
    float st[2] = {0.0f, 0.0f};  // predict-region g1 stash

    __syncthreads();
    // prologue: g1(0) = act(b1 + x0*wih1)
    #pragma unroll
    for (int rr = 0; rr < 2; ++rr) {
        const float v = bb1[rr] + x_lds[0] * wih[rr];
        const float a = 1.0f - mg[rr] * __fdividef(1.0f, __expf(mg[rr] * v) + 1.0f);
        if (rr == 0) g1[r0] = a; else if (wr1) g1[r1] = a;
    }
    __syncthreads();

    const float4* h1q = (const float4*)h1buf;
    const float4* h2q = (const float4*)h2buf;

    int i = 0;
    // ================= teacher region: i = 0 .. T-2 =================
    for (; i < T - 1; ++i) {
        // ---- U-phase: wave0 = U1(i); wave1 = U2(i-1) + out(i-1) ----
        if (wv == 0 && ln < Hh) {
            const float iA = g1[ln], fA = g1[ln + Hh], gA = g1[ln + 2*Hh], oA = g1[ln + 3*Hh];
            const float cn = fA * c1r + iA * gA;
            c1r = cn;
            const float th = 1.0f - __fdividef(2.0f, __expf(2.0f * cn) + 1.0f);
            h1buf[ln] = oA * th;
        }
        if (wv == 1 && i > 0) {
            float part = 0.0f;
            if (ln < Hh) {
                const float iA = g2[ln], fA = g2[ln + Hh], gA = g2[ln + 2*Hh], oA = g2[ln + 3*Hh];
                const float cn = fA * c2r + iA * gA;
                c2r = cn;
                const float th = 1.0f - __fdividef(2.0f, __expf(2.0f * cn) + 1.0f);
                const float hn = oA * th;
                h2buf[ln] = hn;
                part = hn * wlin_l;
            }
            #pragma unroll
            for (int off = 32; off > 0; off >>= 1) part += __shfl_down(part, off);
            if (ln == 0) out[(size_t)b * S + (i - 1)] = part + blin;
        }
        __syncthreads();

        // ---- G-phase: g2(i) and g1(i+1), one h1/h2 broadcast pass ----
        {
            float A0[2]={0,0}, A1[2]={0,0};   // wi2·h1
            float S0[2]={0,0}, S1[2]={0,0};   // w1·h1 (g1 stash)
            float D0[2]={0,0}, D1[2]={0,0};   // wh2·h2
            #pragma unroll
            for (int t = 0; t < 13; ++t) {
                const float4 p = h1q[t];
                const float4 q = h2q[t];
                #pragma unroll
                for (int rr = 0; rr < 2; ++rr) {
                    A0[rr] += wi2[rr][4*t+0]*p.x + wi2[rr][4*t+2]*p.z;
                    A1[rr] += wi2[rr][4*t+1]*p.y + wi2[rr][4*t+3]*p.w;
                    S0[rr] += w1 [rr][4*t+0]*p.x + w1 [rr][4*t+2]*p.z;
                    S1[rr] += w1 [rr][4*t+1]*p.y + w1 [rr][4*t+3]*p.w;
                    D0[rr] += wh2[rr][4*t+0]*q.x + wh2[rr][4*t+2]*q.z;
                    D1[rr] += wh2[rr][4*t+1]*q.y + wh2[rr][4*t+3]*q.w;
                }
            }
            const float xin = x_lds[i + 1];
            #pragma unroll
            for (int rr = 0; rr < 2; ++rr) {
                const float v2  = bb2[rr] + (A0[rr] + A1[rr]) + (D0[rr] + D1[rr]);
                const float g2v = 1.0f - mg[rr] * __fdividef(1.0f, __expf(mg[rr] * v2) + 1.0f);
                const float v1  = bb1[rr] + (S0[rr] + S1[rr]) + xin * wih[rr];
                const float g1v = 1.0f - mg[rr] * __fdividef(1.0f, __expf(mg[rr] * v1) + 1.0f);
                if (rr == 0) { g2[r0] = g2v; g1[r0] = g1v; }
                else if (wr1) { g2[r1] = g2v; g1[r1] = g1v; }
            }
        }
        __syncthreads();
    }

    // ================= predict region: i = T-1 .. S-1 =================
    for (; i < S; ++i) {
        // ---- UA: wave0 = U1(i); first iter wave1 drains U2(T-2)+out(T-2) ----
        if (wv == 0 && ln < Hh) {
            const float iA = g1[ln], fA = g1[ln + Hh], gA = g1[ln + 2*Hh], oA = g1[ln + 3*Hh];
            const float cn = fA * c1r + iA * gA;
            c1r = cn;
            const float th = 1.0f - __fdividef(2.0f, __expf(2.0f * cn) + 1.0f);
            h1buf[ln] = oA * th;
        }
        if (i == T - 1 && wv == 1) {
            float part = 0.0f;
            if (ln < Hh) {
                const float iA = g2[ln], fA = g2[ln + Hh], gA = g2[ln + 2*Hh], oA = g2[ln + 3*Hh];
                const float cn = fA * c2r + iA * gA;
                c2r = cn;
                const float th = 1.0f - __fdividef(2.0f, __expf(2.0f * cn) + 1.0f);
                const float hn = oA * th;
                h2buf[ln] = hn;
                part = hn * wlin_l;
            }
            #pragma unroll
            for (int off = 32; off > 0; off >>= 1) part += __shfl_down(part, off);
            if (ln == 0) out[(size_t)b * S + (i - 1)] = part + blin;
        }
        __syncthreads();

        // ---- GA: g2(i) + stash w1·h1(i) ----
        {
            float A0[2]={0,0}, A1[2]={0,0}, S0[2]={0,0}, S1[2]={0,0}, D0[2]={0,0}, D1[2]={0,0};
            #pragma unroll
            for (int t = 0; t < 13; ++t) {
                const float4 p = h1q[t];
                const float4 q = h2q[t];
                #pragma unroll
                for (int rr = 0; rr < 2; ++rr) {
                    A0[rr] += wi2[rr][4*t+0]*p.x + wi2[rr][4*t+2]*p.z;
                    A1[rr] += wi2[rr][4*t+1]*p.y + wi2[rr][4*t+3]*p.w;
                    S0[rr] += w1 [rr][4*t+0]*p.x + w1 [rr][4*t+2]*p.z;
                    S1[rr] += w1 [rr][4*t+1]*p.y + w1 [rr][4*t+3]*p.w;
                    D0[rr] += wh2[rr][4*t+0]*q.x + wh2[rr][4*t+2]*q.z;
                    D1[rr] += wh2[rr][4*t+1]*q.y + wh2[rr][4*t+3]*q.w;
                }
            }
            #pragma unroll
            for (int rr = 0; rr < 2; ++rr) {
                const float v2  = bb2[rr] + (A0[rr] + A1[rr]) + (D0[rr] + D1[rr]);
                const float g2v = 1.0f - mg[rr] * __fdividef(1.0f, __expf(mg[rr] * v2) + 1.0f);
                st[rr] = S0[rr] + S1[rr];
                if (rr == 0) g2[r0] = g2v; else if (wr1) g2[r1] = g2v;
            }
        }
        __syncthreads();

        // ---- UB: wave1 = U2(i) + out(i) ----
        if (wv == 1) {
            float part = 0.0f;
            if (ln < Hh) {
                const float iA = g2[ln], fA = g2[ln + Hh], gA = g2[ln + 2*Hh], oA = g2[ln + 3*Hh];
                const float cn = fA * c2r + iA * gA;
                c2r = cn;
                const float th = 1.0f - __fdividef(2.0f, __expf(2.0f * cn) + 1.0f);
                const float hn = oA * th;
                h2buf[ln] = hn;
                part = hn * wlin_l;
            }
            #pragma unroll
            for (int off = 32; off > 0; off >>= 1) part += __shfl_down(part, off);
            if (ln == 0) {
                const float o = part + blin;
                out[(size_t)b * S + i] = o;
                o_lds = o;
            }
        }
        __syncthreads();

        // ---- GB: g1(i+1) = act(b1 + stash + o(i)*wih1) ----
        if (i + 1 < S) {
            const float oin = o_lds;
            #pragma unroll
            for (int rr = 0; rr < 2; ++rr) {
                const float v1  = bb1[rr] + st[rr] + oin * wih[rr];
                const float g1v = 1.0f - mg[rr] * __fdividef(1.0f, __expf(mg[rr] * v1) + 1.0f);
                if (rr == 0) g1[r0] = g1v; else if (wr1) g1[r1] = g1v;
            }
        }
        __syncthreads();
    }
}

extern "C" void kernel_launch(void* const* d_in, const int* in_sizes, int n_in,
                              void* d_out, int out_size, void* d_ws, size_t ws_size,
                              hipStream_t stream) {
    const float* x      = (const float*)d_in[0];
    const float* W_ih1  = (const float*)d_in[1];
    const float* W_hh1  = (const float*)d_in[2];
    const float* b_ih1  = (const float*)d_in[3];
    const float* b_hh1  = (const float*)d_in[4];
    const float* W_ih2  = (const float*)d_in[5];
    const float* W_hh2  = (const float*)d_in[6];
    const float* b_ih2  = (const float*)d_in[7];
    const float* b_hh2  = (const float*)d_in[8];
    const float* W_lin  = (const float*)d_in[9];
    const float* b_lin  = (const float*)d_in[10];
    const int*   pred   = (const int*)d_in[11];
    float* out = (float*)d_out;

    const int B = 512;
    const int T = in_sizes[0] / B;   // 1024

    dim3 grid(B), block(NT);
    hipLaunchKernelGGL(sine_lstm_kernel, grid, block, 0, stream,
                       x, W_ih1, W_hh1, b_ih1, b_hh1,
                       W_ih2, W_hh2, b_ih2, b_hh2,
                       W_lin, b_lin, pred, out, T);
}

// Round 6
// 2356.335 us; speedup vs baseline: 1.4127x; 1.4127x over previous
//
#include <hip/hip_runtime.h>

// SineLSTM R6: MFMA reformulation. Per block: 16 batch rows in the MFMA
// N-dim; gates[200x16] = W[200x50] @ H[50x16] via mfma_f32_16x16x32_bf16,
// 3-term split-bf16 (Whi*hhi + Whi*hlo + Wlo*hhi) for ~fp32 accuracy.
// Weight rows permuted to (i,f,g,o)-interleaved so C-layout (col=lane&15,
// row=4*quad+reg) makes each lane own all 4 gates of one (unit,row):
// cell update is lane-local, c in VGPR. h round-trips LDS packed hi|lo,
// lane-divergent (8 b128/wave/step vs R2's 1200 broadcast ds_reads).
// 8 waves x 2 M-tiles: A-frags 96 VGPR/thread -> fits 256, no spill.

#define Hh   50
#define G4   200
#define NROW 16
#define NTHR 512

typedef __attribute__((ext_vector_type(8))) short short8;
typedef __attribute__((ext_vector_type(4))) float f32x4;

static __device__ __forceinline__ unsigned short f2bf(float v) {
    unsigned u = __float_as_uint(v);
    unsigned r = u + 0x7FFFu + ((u >> 16) & 1u);
    return (unsigned short)(r >> 16);
}
static __device__ __forceinline__ float bf2f(unsigned short h) {
    return __uint_as_float(((unsigned)h) << 16);
}
static __device__ __forceinline__ float sigf(float v) {
    return __fdividef(1.0f, 1.0f + __expf(-v));
}
static __device__ __forceinline__ float tanhv(float v) {
    return 1.0f - __fdividef(2.0f, __expf(2.0f * v) + 1.0f);
}

extern "C" __global__ __launch_bounds__(NTHR, 2)
void sine_lstm_kernel(const float* __restrict__ x,
                      const float* __restrict__ W_ih1,
                      const float* __restrict__ W_hh1,
                      const float* __restrict__ b_ih1,
                      const float* __restrict__ b_hh1,
                      const float* __restrict__ W_ih2,
                      const float* __restrict__ W_hh2,
                      const float* __restrict__ b_ih2,
                      const float* __restrict__ b_hh2,
                      const float* __restrict__ W_lin,
                      const float* __restrict__ b_lin,
                      const int*   __restrict__ predict_p,
                      float* __restrict__ out,
                      int T)
{
    // Hp*: packed h (hi bf16 <<16 | lo bf16), [row n][unit k], k padded to 64
    __shared__ __align__(16) unsigned Hp1[NROW][68], Hp2[NROW][68];
    __shared__ __align__(16) float x_tile[NROW][65];
    __shared__ float Opart[NROW][9];
    __shared__ float o_buf[NROW];

    const int tid = threadIdx.x;
    const int wv  = tid >> 6;        // wave 0..7
    const int L   = tid & 63;        // lane
    const int n   = L & 15;          // batch row within block
    const int q   = L >> 4;          // quad
    const int b0  = blockIdx.x * NROW;
    const int S   = T + *predict_p;

    // ---- LDS init ----
    for (int i = tid; i < NROW * 68; i += NTHR) {
        (&Hp1[0][0])[i] = 0u; (&Hp2[0][0])[i] = 0u;
    }
    for (int i = tid; i < NROW * 64; i += NTHR) {
        int r = i >> 6, c = i & 63;
        x_tile[r][c] = x[(size_t)(b0 + r) * T + c];
    }
    if (tid < NROW) { o_buf[tid] = 0.0f; }

    // ---- this wave's two M-tiles (tiles 13..15 are all-zero pads) ----
    const int mt[2] = { wv, 8 + wv };

    // ---- static A-frags (weights, permuted rows p=4u+g), hi/lo split ----
    short8 wi2h[2][2], wi2l[2][2], wh2h[2][2], wh2l[2][2], w1h[2][2], w1l[2][2];
    #pragma unroll
    for (int t = 0; t < 2; ++t) {
        #pragma unroll
        for (int kt = 0; kt < 2; ++kt) {
            const int p = 16 * mt[t] + n;   // permuted row
            #pragma unroll
            for (int j = 0; j < 8; ++j) {
                const int k = kt * 32 + q * 8 + j;
                float vi2 = 0.f, vh2 = 0.f, v1 = 0.f;
                if (p < G4 && k < Hh) {
                    const int u = p >> 2, g = p & 3;
                    const int row = g * Hh + u;
                    vi2 = W_ih2[row * Hh + k];
                    vh2 = W_hh2[row * Hh + k];
                    v1  = W_hh1[row * Hh + k];
                }
                unsigned short hh;
                hh = f2bf(vi2); wi2h[t][kt][j] = (short)hh; wi2l[t][kt][j] = (short)f2bf(vi2 - bf2f(hh));
                hh = f2bf(vh2); wh2h[t][kt][j] = (short)hh; wh2l[t][kt][j] = (short)f2bf(vh2 - bf2f(hh));
                hh = f2bf(v1);  w1h [t][kt][j] = (short)hh; w1l [t][kt][j] = (short)f2bf(v1  - bf2f(hh));
            }
        }
    }

    // ---- per-lane row params: tile t, reg r -> unit u=4*mt+q, gate r ----
    float wih1r[2][4], bb1[2][4], bb2[2][4], wlin2[2];
    #pragma unroll
    for (int t = 0; t < 2; ++t) {
        const int u = 4 * mt[t] + q;
        wlin2[t] = (u < Hh) ? W_lin[u] : 0.0f;
        #pragma unroll
        for (int r = 0; r < 4; ++r) {
            if (u < Hh) {
                const int row = r * Hh + u;
                wih1r[t][r] = W_ih1[row];
                bb1[t][r]   = b_ih1[row] + b_hh1[row];
                bb2[t][r]   = b_ih2[row] + b_hh2[row];
            } else { wih1r[t][r] = 0.f; bb1[t][r] = 0.f; bb2[t][r] = 0.f; }
        }
    }

    const float blin = b_lin[0];
    f32x4 st[2];  st[0] = (f32x4){0,0,0,0}; st[1] = (f32x4){0,0,0,0};
    f32x4 g2a[2]; g2a[0] = (f32x4){0,0,0,0}; g2a[1] = (f32x4){0,0,0,0};
    float c1v[2] = {0.f, 0.f}, c2v[2] = {0.f, 0.f};

    __syncthreads();

    #define PHASE_U1(XIN)                                                        \
        {   const float xin = (XIN);                                             \
            _Pragma("unroll")                                                    \
            for (int t = 0; t < 2; ++t) {                                        \
                const float p0 = st[t][0] + xin * wih1r[t][0] + bb1[t][0];       \
                const float p1 = st[t][1] + xin * wih1r[t][1] + bb1[t][1];       \
                const float p2 = st[t][2] + xin * wih1r[t][2] + bb1[t][2];       \
                const float p3 = st[t][3] + xin * wih1r[t][3] + bb1[t][3];       \
                const float ig = sigf(p0), fg = sigf(p1);                        \
                const float gg = tanhv(p2), og = sigf(p3);                       \
                const float c = fg * c1v[t] + ig * gg; c1v[t] = c;               \
                const float h = og * tanhv(c);                                   \
                const unsigned short hh = f2bf(h);                               \
                const unsigned short hl = f2bf(h - bf2f(hh));                    \
                Hp1[n][4 * mt[t] + q] = ((unsigned)hh << 16) | (unsigned)hl;     \
            } }

    #define PHASE_MFMA()                                                         \
        {   short8 b1h[2], b1l[2], b2h[2], b2l[2];                               \
            _Pragma("unroll")                                                    \
            for (int kt = 0; kt < 2; ++kt) {                                     \
                const uint4* pp = (const uint4*)&Hp1[n][kt * 32 + q * 8];        \
                uint4 A = pp[0], B = pp[1];                                      \
                unsigned e[8] = {A.x, A.y, A.z, A.w, B.x, B.y, B.z, B.w};        \
                _Pragma("unroll")                                                \
                for (int j = 0; j < 8; ++j) {                                    \
                    b1h[kt][j] = (short)(e[j] >> 16);                            \
                    b1l[kt][j] = (short)(e[j] & 0xFFFFu);                        \
                }                                                                \
                const uint4* p2q = (const uint4*)&Hp2[n][kt * 32 + q * 8];       \
                uint4 C = p2q[0], D = p2q[1];                                    \
                unsigned f[8] = {C.x, C.y, C.z, C.w, D.x, D.y, D.z, D.w};        \
                _Pragma("unroll")                                                \
                for (int j = 0; j < 8; ++j) {                                    \
                    b2h[kt][j] = (short)(f[j] >> 16);                            \
                    b2l[kt][j] = (short)(f[j] & 0xFFFFu);                        \
                }                                                                \
            }                                                                    \
            _Pragma("unroll")                                                    \
            for (int t = 0; t < 2; ++t) {                                        \
                f32x4 acc = (f32x4){0,0,0,0};                                    \
                _Pragma("unroll")                                                \
                for (int kt = 0; kt < 2; ++kt) {                                 \
                    acc = __builtin_amdgcn_mfma_f32_16x16x32_bf16(wi2h[t][kt], b1h[kt], acc, 0,0,0); \
                    acc = __builtin_amdgcn_mfma_f32_16x16x32_bf16(wi2h[t][kt], b1l[kt], acc, 0,0,0); \
                    acc = __builtin_amdgcn_mfma_f32_16x16x32_bf16(wi2l[t][kt], b1h[kt], acc, 0,0,0); \
                    acc = __builtin_amdgcn_mfma_f32_16x16x32_bf16(wh2h[t][kt], b2h[kt], acc, 0,0,0); \
                    acc = __builtin_amdgcn_mfma_f32_16x16x32_bf16(wh2h[t][kt], b2l[kt], acc, 0,0,0); \
                    acc = __builtin_amdgcn_mfma_f32_16x16x32_bf16(wh2l[t][kt], b2h[kt], acc, 0,0,0); \
                }                                                                \
                g2a[t] = acc;                                                    \
                f32x4 sa = (f32x4){0,0,0,0};                                     \
                _Pragma("unroll")                                                \
                for (int kt = 0; kt < 2; ++kt) {                                 \
                    sa = __builtin_amdgcn_mfma_f32_16x16x32_bf16(w1h[t][kt], b1h[kt], sa, 0,0,0);    \
                    sa = __builtin_amdgcn_mfma_f32_16x16x32_bf16(w1h[t][kt], b1l[kt], sa, 0,0,0);    \
                    sa = __builtin_amdgcn_mfma_f32_16x16x32_bf16(w1l[t][kt], b1h[kt], sa, 0,0,0);    \
                }                                                                \
                st[t] = sa;                                                      \
            } }

    #define PHASE_U2()                                                          \
        {   float po = 0.0f;                                                     \
            _Pragma("unroll")                                                    \
            for (int t = 0; t < 2; ++t) {                                        \
                const float p0 = g2a[t][0] + bb2[t][0];                          \
                const float p1 = g2a[t][1] + bb2[t][1];                          \
                const float p2 = g2a[t][2] + bb2[t][2];                          \
                const float p3 = g2a[t][3] + bb2[t][3];                          \
                const float ig = sigf(p0), fg = sigf(p1);                        \
                const float gg = tanhv(p2), og = sigf(p3);                       \
                const float c = fg * c2v[t] + ig * gg; c2v[t] = c;               \
                const float h = og * tanhv(c);                                   \
                const unsigned short hh = f2bf(h);                               \
                const unsigned short hl = f2bf(h - bf2f(hh));                    \
                Hp2[n][4 * mt[t] + q] = ((unsigned)hh << 16) | (unsigned)hl;     \
                po += wlin2[t] * h;                                              \
            }                                                                    \
            po += __shfl_xor(po, 16);                                            \
            po += __shfl_xor(po, 32);                                            \
            if (L < 16) Opart[L][wv] = po; }

    int s = 0;
    // ================= teacher region: s = 0 .. T-2 (2 barriers) =========
    for (; s < T - 1; ++s) {
        PHASE_U1(x_tile[n][s & 63]);
        __syncthreads();                                   // B1

        if (wv == 7 && L < 16 && s > 0) {                  // out(s-1)
            float o = blin;
            #pragma unroll
            for (int w = 0; w < 8; ++w) o += Opart[L][w];
            out[(size_t)(b0 + L) * S + (s - 1)] = o;
        }
        if (((s + 1) & 63) == 0 && (s + 1) < T) {          // stage next x tile
            for (int i = tid; i < NROW * 64; i += NTHR) {
                int r = i >> 6, c = i & 63;
                x_tile[r][c] = x[(size_t)(b0 + r) * T + (s + 1) + c];
            }
        }
        PHASE_MFMA();
        __syncthreads();                                   // B2

        PHASE_U2();
        // no end barrier: Hp2/Opart written here are read after B1(s+1)
    }

    // ================= tail region: s = T-1 .. S-1 (4 barriers) ==========
    for (; s < S; ++s) {
        PHASE_U1((s < T) ? x_tile[n][s & 63] : o_buf[n]);
        __syncthreads();                                   // B1

        if (s == T - 1 && wv == 7 && L < 16 && s > 0) {    // pending out(T-2)
            float o = blin;
            #pragma unroll
            for (int w = 0; w < 8; ++w) o += Opart[L][w];
            out[(size_t)(b0 + L) * S + (s - 1)] = o;
        }
        PHASE_MFMA();
        __syncthreads();                                   // B2

        PHASE_U2();
        __syncthreads();                                   // B3

        if (wv == 7 && L < 16) {                           // out(s) + feedback
            float o = blin;
            #pragma unroll
            for (int w = 0; w < 8; ++w) o += Opart[L][w];
            out[(size_t)(b0 + L) * S + s] = o;
            o_buf[L] = o;
        }
        __syncthreads();                                   // B4
    }

    #undef PHASE_U1
    #undef PHASE_MFMA
    #undef PHASE_U2
}

extern "C" void kernel_launch(void* const* d_in, const int* in_sizes, int n_in,
                              void* d_out, int out_size, void* d_ws, size_t ws_size,
                              hipStream_t stream) {
    const float* x      = (const float*)d_in[0];
    const float* W_ih1  = (const float*)d_in[1];
    const float* W_hh1  = (const float*)d_in[2];
    const float* b_ih1  = (const float*)d_in[3];
    const float* b_hh1  = (const float*)d_in[4];
    const float* W_ih2  = (const float*)d_in[5];
    const float* W_hh2  = (const float*)d_in[6];
    const float* b_ih2  = (const float*)d_in[7];
    const float* b_hh2  = (const float*)d_in[8];
    const float* W_lin  = (const float*)d_in[9];
    const float* b_lin  = (const float*)d_in[10];
    const int*   pred   = (const int*)d_in[11];
    float* out = (float*)d_out;

    const int B = 512;
    const int T = in_sizes[0] / B;   // 1024

    dim3 grid(B / NROW), block(NTHR);
    hipLaunchKernelGGL(sine_lstm_kernel, grid, block, 0, stream,
                       x, W_ih1, W_hh1, b_ih1, b_hh1,
                       W_ih2, W_hh2, b_ih2, b_hh2,
                       W_lin, b_lin, pred, out, T);
}

// Round 7
// 2003.035 us; speedup vs baseline: 1.6619x; 1.1764x over previous
//
#include <hip/hip_runtime.h>

// SineLSTM R7: R6 MFMA skeleton (validated correct) minus its three stalls.
//  - outputs buffered in LDS, flushed as float4 bursts every 16 steps
//    (R6 paid a vmcnt(0) store-ack before B2 EVERY step).
//  - whole x resident in LDS (66KB) -- no in-loop staging.
//  - f16 instead of bf16-3-term: h stored hi+lo f16, weights single f16
//    (f16 W-quant error ~2.5e-5 replaces the Wlo term). 24 MFMAs/wave
//    (was 36), zero unpack VALU (b128 loads ARE the half8 fragments).
//  - acc chains split by kt: two independent 4-chains, not one 12-chain.
//  - waves 5..7 skip their all-pad second tile.

#define Hh   50
#define G4   200
#define NROW 16
#define NTHR 512
#define TLEN 1024

typedef __attribute__((ext_vector_type(8))) _Float16 half8;
typedef __attribute__((ext_vector_type(4))) float f32x4;

static __device__ __forceinline__ float sigf(float v) {
    return __fdividef(1.0f, 1.0f + __expf(-v));
}
static __device__ __forceinline__ float tanhv(float v) {
    return 1.0f - __fdividef(2.0f, __expf(2.0f * v) + 1.0f);
}

extern "C" __global__ __launch_bounds__(NTHR, 2)
void sine_lstm_kernel(const float* __restrict__ x,
                      const float* __restrict__ W_ih1,
                      const float* __restrict__ W_hh1,
                      const float* __restrict__ b_ih1,
                      const float* __restrict__ b_hh1,
                      const float* __restrict__ W_ih2,
                      const float* __restrict__ W_hh2,
                      const float* __restrict__ b_ih2,
                      const float* __restrict__ b_hh2,
                      const float* __restrict__ W_lin,
                      const float* __restrict__ b_lin,
                      const int*   __restrict__ predict_p,
                      float* __restrict__ out,
                      int T)
{
    __shared__ __align__(16) float x_all[NROW][TLEN + 2];        // stride 1026
    __shared__ __align__(16) _Float16 H1h[NROW][72], H1l[NROW][72];
    __shared__ __align__(16) _Float16 H2h[NROW][72], H2l[NROW][72];
    __shared__ float Opart[NROW][9];
    __shared__ __align__(16) float obuf[NROW][20];
    __shared__ float o_feed[NROW];

    const int tid = threadIdx.x;
    const int wv  = tid >> 6;        // wave 0..7
    const int L   = tid & 63;
    const int n   = L & 15;          // batch row (MFMA col)
    const int q   = L >> 4;          // quad
    const int b0  = blockIdx.x * NROW;
    const int S   = T + *predict_p;

    // ---- LDS init ----
    for (int i = tid; i < NROW * 72; i += NTHR) {
        (&H1h[0][0])[i] = (_Float16)0.f; (&H1l[0][0])[i] = (_Float16)0.f;
        (&H2h[0][0])[i] = (_Float16)0.f; (&H2l[0][0])[i] = (_Float16)0.f;
    }
    for (int i = tid; i < NROW * TLEN; i += NTHR) {              // whole x
        int r = i >> 10, c = i & 1023;
        x_all[r][c] = x[(size_t)(b0 + r) * T + c];
    }

    // ---- this wave's two M-tiles; tiles >= 13 are all-pad ----
    const int mt[2] = { wv, 8 + wv };
    const bool act1 = (16 * mt[1] < G4);     // waves 5,6,7: false

    // ---- A-fragments: single-f16 weights, permuted rows p = 4u+g ----
    half8 wa1[2][2], wa2i[2][2], wa2h[2][2];
    #pragma unroll
    for (int t = 0; t < 2; ++t) {
        #pragma unroll
        for (int kt = 0; kt < 2; ++kt) {
            const int p = 16 * mt[t] + n;
            #pragma unroll
            for (int j = 0; j < 8; ++j) {
                const int k = kt * 32 + q * 8 + j;
                float v1 = 0.f, vi2 = 0.f, vh2 = 0.f;
                if (p < G4 && k < Hh) {
                    const int u = p >> 2, g = p & 3;
                    const int row = g * Hh + u;
                    v1  = W_hh1[row * Hh + k];
                    vi2 = W_ih2[row * Hh + k];
                    vh2 = W_hh2[row * Hh + k];
                }
                wa1 [t][kt][j] = (_Float16)v1;
                wa2i[t][kt][j] = (_Float16)vi2;
                wa2h[t][kt][j] = (_Float16)vh2;
            }
        }
    }

    // ---- per-lane cell params: tile t, reg r -> unit u = 4*mt+q, gate r ----
    float wih1r[2][4], bb1[2][4], bb2[2][4], wlin2[2];
    #pragma unroll
    for (int t = 0; t < 2; ++t) {
        const int u = 4 * mt[t] + q;
        wlin2[t] = (u < Hh) ? W_lin[u] : 0.0f;
        #pragma unroll
        for (int r = 0; r < 4; ++r) {
            if (u < Hh) {
                const int row = r * Hh + u;
                wih1r[t][r] = W_ih1[row];
                bb1[t][r]   = b_ih1[row] + b_hh1[row];
                bb2[t][r]   = b_ih2[row] + b_hh2[row];
            } else { wih1r[t][r] = 0.f; bb1[t][r] = 0.f; bb2[t][r] = 0.f; }
        }
    }

    const float blin = b_lin[0];
    f32x4 st[2];  st[0] = (f32x4){0,0,0,0}; st[1] = (f32x4){0,0,0,0};
    f32x4 g2a[2]; g2a[0] = (f32x4){0,0,0,0}; g2a[1] = (f32x4){0,0,0,0};
    float c1v[2] = {0.f, 0.f}, c2v[2] = {0.f, 0.f};

    auto cellmath = [&](float p0, float p1, float p2, float p3, float& c) -> float {
        const float ig = sigf(p0), fg = sigf(p1);
        const float gg = tanhv(p2), og = sigf(p3);
        const float cn = fg * c + ig * gg; c = cn;
        return og * tanhv(cn);
    };

    auto do_u1 = [&](float xin) {
        #pragma unroll
        for (int t = 0; t < 2; ++t) {
            if (t == 0 || act1) {
                const float h = cellmath(st[t][0] + xin * wih1r[t][0] + bb1[t][0],
                                         st[t][1] + xin * wih1r[t][1] + bb1[t][1],
                                         st[t][2] + xin * wih1r[t][2] + bb1[t][2],
                                         st[t][3] + xin * wih1r[t][3] + bb1[t][3],
                                         c1v[t]);
                const int u = 4 * mt[t] + q;
                const _Float16 hh = (_Float16)h;
                H1h[n][u] = hh;
                H1l[n][u] = (_Float16)(h - (float)hh);
            }
        }
    };

    auto do_mfma = [&]() {
        half8 b1h[2], b1l[2], b2h[2], b2l[2];
        #pragma unroll
        for (int kt = 0; kt < 2; ++kt) {
            const int off = kt * 32 + q * 8;
            b1h[kt] = *(const half8*)&H1h[n][off];
            b1l[kt] = *(const half8*)&H1l[n][off];
            b2h[kt] = *(const half8*)&H2h[n][off];
            b2l[kt] = *(const half8*)&H2l[n][off];
        }
        #pragma unroll
        for (int t = 0; t < 2; ++t) {
            if (t == 0 || act1) {
                f32x4 aA = (f32x4){0,0,0,0}, aB = (f32x4){0,0,0,0};
                aA = __builtin_amdgcn_mfma_f32_16x16x32_f16(wa2i[t][0], b1h[0], aA, 0,0,0);
                aA = __builtin_amdgcn_mfma_f32_16x16x32_f16(wa2i[t][0], b1l[0], aA, 0,0,0);
                aA = __builtin_amdgcn_mfma_f32_16x16x32_f16(wa2h[t][0], b2h[0], aA, 0,0,0);
                aA = __builtin_amdgcn_mfma_f32_16x16x32_f16(wa2h[t][0], b2l[0], aA, 0,0,0);
                aB = __builtin_amdgcn_mfma_f32_16x16x32_f16(wa2i[t][1], b1h[1], aB, 0,0,0);
                aB = __builtin_amdgcn_mfma_f32_16x16x32_f16(wa2i[t][1], b1l[1], aB, 0,0,0);
                aB = __builtin_amdgcn_mfma_f32_16x16x32_f16(wa2h[t][1], b2h[1], aB, 0,0,0);
                aB = __builtin_amdgcn_mfma_f32_16x16x32_f16(wa2h[t][1], b2l[1], aB, 0,0,0);
                g2a[t] = aA + aB;
                f32x4 sA = (f32x4){0,0,0,0}, sB = (f32x4){0,0,0,0};
                sA = __builtin_amdgcn_mfma_f32_16x16x32_f16(wa1[t][0], b1h[0], sA, 0,0,0);
                sA = __builtin_amdgcn_mfma_f32_16x16x32_f16(wa1[t][0], b1l[0], sA, 0,0,0);
                sB = __builtin_amdgcn_mfma_f32_16x16x32_f16(wa1[t][1], b1h[1], sB, 0,0,0);
                sB = __builtin_amdgcn_mfma_f32_16x16x32_f16(wa1[t][1], b1l[1], sB, 0,0,0);
                st[t] = sA + sB;
            }
        }
    };

    auto do_u2 = [&]() {
        float po = 0.0f;
        #pragma unroll
        for (int t = 0; t < 2; ++t) {
            if (t == 0 || act1) {
                const float h = cellmath(g2a[t][0] + bb2[t][0],
                                         g2a[t][1] + bb2[t][1],
                                         g2a[t][2] + bb2[t][2],
                                         g2a[t][3] + bb2[t][3],
                                         c2v[t]);
                const int u = 4 * mt[t] + q;
                const _Float16 hh = (_Float16)h;
                H2h[n][u] = hh;
                H2l[n][u] = (_Float16)(h - (float)hh);
                po += wlin2[t] * h;
            }
        }
        po += __shfl_xor(po, 16);
        po += __shfl_xor(po, 32);
        if (L < 16) Opart[L][wv] = po;
    };

    // wave 7, lanes<16: sum partials for out index idx, buffer, burst-flush
    auto out_collect = [&](int idx) -> float {
        float o = blin;
        #pragma unroll
        for (int w = 0; w < 8; ++w) o += Opart[L][w];
        obuf[L][idx & 15] = o;
        if ((idx & 15) == 15) {
            const size_t base = (size_t)(b0 + L) * S + (idx - 15);
            #pragma unroll
            for (int m = 0; m < 4; ++m) {
                const float4 v = *(const float4*)&obuf[L][4 * m];
                *(float4*)&out[base + 4 * m] = v;
            }
        }
        return o;
    };

    __syncthreads();

    int s = 0;
    // ================= teacher region: s = 0 .. T-2 (2 barriers) =========
    for (; s < T - 1; ++s) {
        do_u1(x_all[n][s]);
        __syncthreads();                              // B1
        if (wv == 7 && L < 16 && s > 0) out_collect(s - 1);
        do_mfma();
        __syncthreads();                              // B2
        do_u2();
        // Hp2/Opart written here are first read after B1(s+1)
    }

    // ================= tail region: s = T-1 .. S-1 (4 barriers) ==========
    for (; s < S; ++s) {
        do_u1((s < T) ? x_all[n][s] : o_feed[n]);
        __syncthreads();                              // B1
        if (s == T - 1 && wv == 7 && L < 16) out_collect(s - 1);
        do_mfma();
        __syncthreads();                              // B2
        do_u2();
        __syncthreads();                              // B3
        if (wv == 7 && L < 16) {
            const float o = out_collect(s);
            o_feed[L] = o;
        }
        __syncthreads();                              // B4
    }
}

extern "C" void kernel_launch(void* const* d_in, const int* in_sizes, int n_in,
                              void* d_out, int out_size, void* d_ws, size_t ws_size,
                              hipStream_t stream) {
    const float* x      = (const float*)d_in[0];
    const float* W_ih1  = (const float*)d_in[1];
    const float* W_hh1  = (const float*)d_in[2];
    const float* b_ih1  = (const float*)d_in[3];
    const float* b_hh1  = (const float*)d_in[4];
    const float* W_ih2  = (const float*)d_in[5];
    const float* W_hh2  = (const float*)d_in[6];
    const float* b_ih2  = (const float*)d_in[7];
    const float* b_hh2  = (const float*)d_in[8];
    const float* W_lin  = (const float*)d_in[9];
    const float* b_lin  = (const float*)d_in[10];
    const int*   pred   = (const int*)d_in[11];
    float* out = (float*)d_out;

    const int B = 512;
    const int T = in_sizes[0] / B;   // 1024

    dim3 grid(B / NROW), block(NTHR);
    hipLaunchKernelGGL(sine_lstm_kernel, grid, block, 0, stream,
                       x, W_ih1, W_hh1, b_ih1, b_hh1,
                       W_ih2, W_hh2, b_ih2, b_hh2,
                       W_lin, b_lin, pred, out, T);
}